// Round 1
// baseline (66.392 us; speedup 1.0000x reference)
//
#include <hip/hip_runtime.h>

#define HH 256
#define WW 256
#define CC 8
#define TILE 32
#define HT 34              // TILE + 2 halo
#define HN (HT * HT)       // 1156 halo pixels

// One block = one 32x32 output tile of one batch image.
// Phase A: cooperative load of 8 affinity channels over the 34x34 halo tile,
//          normalize in place (aff_c / sum|aff|), store raw channel-sum.
// Phase B: per output pixel, gather 8 normalized neighbor values + center term.
__global__ __launch_bounds__(256) void cspn_kernel(
    const float* __restrict__ aff,   // [B, 8, H, W]
    const float* __restrict__ cur,   // [B, 1, H, W]
    const float* __restrict__ coa,   // [B, 1, H, W]
    float* __restrict__ out)         // [B, 1, H, W]
{
    __shared__ float s_aff[CC][HN];  // normalized affinity, halo tile
    __shared__ float s_rsum[HN];     // raw sum over channels (pre-normalization)

    const int b   = blockIdx.z;
    const int ty0 = blockIdx.y * TILE;
    const int tx0 = blockIdx.x * TILE;
    const int tid = threadIdx.x;

    const float* __restrict__ affb = aff + (size_t)b * CC * (HH * WW);

    // ---- Phase A: load + normalize halo tile ----
    for (int i = tid; i < HN; i += 256) {
        const int row = i / HT;
        const int col = i - row * HT;
        const int gy  = ty0 - 1 + row;
        const int gx  = tx0 - 1 + col;
        const bool inb = ((unsigned)gy < HH) && ((unsigned)gx < WW);
        const int base = gy * WW + gx;

        float v[CC];
        float s = 0.f, rs = 0.f;
#pragma unroll
        for (int c = 0; c < CC; ++c) {
            float x = inb ? affb[c * (HH * WW) + base] : 0.f;
            v[c] = x;
            s  += fabsf(x);
            rs += x;
        }
        const float invs = (s > 0.f) ? (1.0f / s) : 0.f;  // 0 for out-of-image halo
#pragma unroll
        for (int c = 0; c < CC; ++c) s_aff[c][i] = v[c] * invs;
        s_rsum[i] = rs;
    }
    __syncthreads();

    // ---- Phase B: gather ----
    const int lx  = tid & 31;        // 0..31 within row
    const int ly0 = tid >> 5;        // 0..7
    const size_t img = (size_t)b * (HH * WW);

#pragma unroll
    for (int j = 0; j < 4; ++j) {
        const int ly = ly0 + j * 8;
        const int gy = ty0 + ly;
        const int gx = tx0 + lx;
        const int hy = ly + 1;
        const int hx = lx + 1;
        const int p  = hy * HT + hx;

        const float c_cur = cur[img + gy * WW + gx];
        const float c_coa = coa[img + gy * WW + gx];
        const float rs    = s_rsum[p];

        // k: (dy,dx) = (k/3-1, k%3-1); channel c = k<4 ? k : k-1 (k!=4)
        // out[y,x] += cur[y,x] * a_c[y-dy, x-dx]
        const float sum_nb =
            s_aff[0][p + HT + 1] +   // k=0: (-1,-1) -> read (hy+1,hx+1)
            s_aff[1][p + HT    ] +   // k=1: (-1, 0)
            s_aff[2][p + HT - 1] +   // k=2: (-1,+1)
            s_aff[3][p + 1     ] +   // k=3: ( 0,-1)
            s_aff[4][p - 1     ] +   // k=5: ( 0,+1)
            s_aff[5][p - HT + 1] +   // k=6: (+1,-1)
            s_aff[6][p - HT    ] +   // k=7: (+1, 0)
            s_aff[7][p - HT - 1];    // k=8: (+1,+1)

        out[img + gy * WW + gx] = c_cur * sum_nb + c_coa * (1.0f - rs);
    }
}

extern "C" void kernel_launch(void* const* d_in, const int* in_sizes, int n_in,
                              void* d_out, int out_size, void* d_ws, size_t ws_size,
                              hipStream_t stream) {
    const float* aff = (const float*)d_in[0];   // [64, 8, 256, 256]
    const float* cur = (const float*)d_in[1];   // [64, 1, 256, 256]
    const float* coa = (const float*)d_in[2];   // [64, 1, 256, 256]
    float* out = (float*)d_out;                 // [64, 1, 256, 256]

    dim3 grid(WW / TILE, HH / TILE, 64);        // 8 x 8 x 64
    dim3 block(256);
    cspn_kernel<<<grid, block, 0, stream>>>(aff, cur, coa, out);
}

// Round 2
// 33.274 us; speedup vs baseline: 1.9953x; 1.9953x over previous
//
#include <hip/hip_runtime.h>

#define HH 256
#define WW 256
#define CC 8
#define TY 16
#define LW (WW + 2)          // padded LDS row: col 0 and 257 are zero
#define NSTRIP (HH / TY)     // 16 strips per image

// One block = one TY-row full-width strip of one image. One thread per column.
// Sliding 4-row ring of NORMALIZED affinity channels in LDS; raw next-row
// values prefetched into registers each iteration; rsum carried in registers.
// out(j,x) = cur(j,x) * [ a0(j+1,x+1)+a1(j+1,x)+a2(j+1,x-1)
//                        +a3(j,  x+1)          +a4(j,  x-1)
//                        +a5(j-1,x+1)+a6(j-1,x)+a7(j-1,x-1) ]
//          + coa(j,x) * (1 - rawsum(j,x)),   a_c = aff_c / sum_c|aff_c|
__global__ __launch_bounds__(256) void cspn_strip(
    const float* __restrict__ aff,   // [B, 8, H, W]
    const float* __restrict__ cur,   // [B, 1, H, W]
    const float* __restrict__ coa,   // [B, 1, H, W]
    float* __restrict__ out)         // [B, 1, H, W]
{
    __shared__ float ring[4][CC][LW];

    // bijective XCD swizzle: 1024 blocks % 8 == 0 -> 128 consecutive per XCD
    // (keeps all 16 strips of an image on one XCD: boundary rows hit L2)
    const int cpx = gridDim.x >> 3;
    int wg = blockIdx.x;
    wg = (wg & 7) * cpx + (wg >> 3);

    const int b  = wg >> 4;                    // image
    const int y0 = (wg & (NSTRIP - 1)) * TY;   // strip start row
    const int x  = threadIdx.x;                // column 0..255

    // zero the x-pad columns once (4 slots x 8 ch x 2 sides = 64 entries)
    if (threadIdx.x < 64) {
        const int s = threadIdx.x >> 4;
        const int c = (threadIdx.x >> 1) & 7;
        ring[s][c][(threadIdx.x & 1) ? (LW - 1) : 0] = 0.f;
    }

    const size_t plane = (size_t)HH * WW;
    const float* __restrict__ ab = aff + (size_t)b * CC * plane;
    const size_t img = (size_t)b * plane;

    // prime: raw row y0-1 (zeros outside image)
    float r[CC];
    {
        const int yy = y0 - 1;
        const bool inb = ((unsigned)yy < HH);
        #pragma unroll
        for (int c = 0; c < CC; ++c)
            r[c] = inb ? ab[c * plane + (size_t)yy * WW + x] : 0.f;
    }
    float rsum_prev = 0.f;

    __syncthreads();

    for (int y = y0 - 1; y <= y0 + TY; ++y) {
        // ---- prefetch raw row y+1 into registers (hides HBM latency) ----
        float n[CC];
        const int yn = y + 1;
        const bool ldn = (yn <= y0 + TY) && ((unsigned)yn < HH);
        #pragma unroll
        for (int c = 0; c < CC; ++c)
            n[c] = ldn ? ab[c * plane + (size_t)yn * WW + x] : 0.f;

        const int j = y - 1;                 // output row finalized this iter
        const bool emit = (j >= y0);         // j < y0+TY always true here
        float cj = 0.f, oj = 0.f;
        if (emit) {
            cj = cur[img + (size_t)j * WW + x];
            oj = coa[img + (size_t)j * WW + x];
        }

        // ---- normalize row y -> ring slot ----
        float s = 0.f, rs = 0.f;
        #pragma unroll
        for (int c = 0; c < CC; ++c) { s += fabsf(r[c]); rs += r[c]; }
        const float invs = (s > 0.f) ? (1.0f / s) : 0.f;  // 0 for off-image rows
        const int slot = (y + 4) & 3;
        #pragma unroll
        for (int c = 0; c < CC; ++c) ring[slot][c][x + 1] = r[c] * invs;

        __syncthreads();

        // ---- gather output row j (needs rows j-1, j, j+1 in ring) ----
        if (emit) {
            const int sp = (y + 4) & 3;      // row j+1 == y
            const int sc = (y + 3) & 3;      // row j
            const int sm = (y + 2) & 3;      // row j-1
            const int xc = x + 1;
            const float sum =
                ring[sp][0][xc + 1] + ring[sp][1][xc] + ring[sp][2][xc - 1] +
                ring[sc][3][xc + 1]                   + ring[sc][4][xc - 1] +
                ring[sm][5][xc + 1] + ring[sm][6][xc] + ring[sm][7][xc - 1];
            out[img + (size_t)j * WW + x] = cj * sum + oj * (1.0f - rsum_prev);
        }

        rsum_prev = rs;                      // rs of row y -> used when j == y
        #pragma unroll
        for (int c = 0; c < CC; ++c) r[c] = n[c];
    }
}

extern "C" void kernel_launch(void* const* d_in, const int* in_sizes, int n_in,
                              void* d_out, int out_size, void* d_ws, size_t ws_size,
                              hipStream_t stream) {
    const float* aff = (const float*)d_in[0];   // [64, 8, 256, 256]
    const float* cur = (const float*)d_in[1];   // [64, 1, 256, 256]
    const float* coa = (const float*)d_in[2];   // [64, 1, 256, 256]
    float* out = (float*)d_out;                 // [64, 1, 256, 256]

    dim3 grid(64 * NSTRIP);                     // 1024 blocks = 4 per CU, all resident
    dim3 block(256);
    cspn_strip<<<grid, block, 0, stream>>>(aff, cur, coa, out);
}